// Round 1
// 1129.216 us; speedup vs baseline: 1.0169x; 1.0169x over previous
//
#include <hip/hip_runtime.h>
#include <cmath>

#define T_STEPS 512
#define BATCH   64
#define ISZ     512
#define HSZ     512
#define EXN     32768   // u64 words per ring slot (64 batches x 512)

// ---------------------------------------------------------------------------
// Tagged-word exchange (proven protocol): one atomic u64 = {tag=t+1, h bits}.
// ---------------------------------------------------------------------------
__device__ __forceinline__ void ex_store(unsigned long long* w, float h, unsigned tag) {
    union { float f; unsigned u; } c; c.f = h;
    const unsigned long long v = ((unsigned long long)tag << 32) | (unsigned long long)c.u;
    __hip_atomic_store(w, v, __ATOMIC_RELAXED, __HIP_MEMORY_SCOPE_AGENT);
}

// ---------------------------------------------------------------------------
// Per-thread dot over a 32-k segment for 2 output rows x 2 batches, then
// in-wave butterfly fold over the 16 ksegs (lane bits 0..3), then pick this
// lane's (jx,b) result. src layout: float4[par*288 + (b*16 + kseg)*9 + i]
// (9-f4 row pad -> kseg bank stride 4, 2-way aliasing = free).
// ---------------------------------------------------------------------------
__device__ __forceinline__ float dot_fold_pick(const float4 (&W)[2][8],
                                               const float4* __restrict__ src,
                                               int parbase4, int kseg,
                                               int jxr, int br) {
    float A00 = 0.f, A01 = 0.f, A10 = 0.f, A11 = 0.f;
    const float4* s0 = src + parbase4 + kseg * 9;   // batch 0
    const float4* s1 = s0 + 144;                    // batch 1 (+16*9 f4)
    #pragma unroll
    for (int i = 0; i < 8; ++i) {
        const float4 h0 = s0[i];
        const float4 h1 = s1[i];
        A00 = fmaf(W[0][i].x, h0.x, A00); A00 = fmaf(W[0][i].y, h0.y, A00);
        A00 = fmaf(W[0][i].z, h0.z, A00); A00 = fmaf(W[0][i].w, h0.w, A00);
        A01 = fmaf(W[0][i].x, h1.x, A01); A01 = fmaf(W[0][i].y, h1.y, A01);
        A01 = fmaf(W[0][i].z, h1.z, A01); A01 = fmaf(W[0][i].w, h1.w, A01);
        A10 = fmaf(W[1][i].x, h0.x, A10); A10 = fmaf(W[1][i].y, h0.y, A10);
        A10 = fmaf(W[1][i].z, h0.z, A10); A10 = fmaf(W[1][i].w, h0.w, A10);
        A11 = fmaf(W[1][i].x, h1.x, A11); A11 = fmaf(W[1][i].y, h1.y, A11);
        A11 = fmaf(W[1][i].z, h1.z, A11); A11 = fmaf(W[1][i].w, h1.w, A11);
    }
    #pragma unroll
    for (int d = 1; d < 16; d <<= 1) {
        A00 += __shfl_xor(A00, d, 64);
        A01 += __shfl_xor(A01, d, 64);
        A10 += __shfl_xor(A10, d, 64);
        A11 += __shfl_xor(A11, d, 64);
    }
    const float a0 = br ? A01 : A00;
    const float a1 = br ? A11 : A10;
    return jxr ? a1 : a0;
}

// ---------------------------------------------------------------------------
// Fully fused RNN: 256 WGs (32 batch-pairs x 8 neuron-slices) x 512 threads,
// 1 WG/CU. Thread (jg 0..31, kseg 0..15): 2 j-rows x 32 k x both batches.
// W_hh AND W_ih slices in registers (64+64 floats, no duplication). xw for
// step t+1 computed after ex_store(t), hidden in the exchange-propagation
// window -> standalone phase-1 GEMM eliminated. One barrier/step; hl/xs
// parity double-buffered; in-wave fold -> wave-autonomous tanh/store tails.
// ---------------------------------------------------------------------------
__global__ __launch_bounds__(512, 2) void rnn_fused(const float* __restrict__ x,
                                                    const float* __restrict__ wih,
                                                    const float* __restrict__ whh,
                                                    float* __restrict__ out,
                                                    unsigned long long* __restrict__ ex) {
    __shared__ __align__(16) float hls[2304];   // [2 par][2 b][16 kseg][9 f4]
    __shared__ __align__(16) float xss[2304];   // same layout, x(t) rows
    const float4* hl4 = (const float4*)hls;
    const float4* xs4 = (const float4*)xss;

    const int tid  = threadIdx.x;
    const int p    = blockIdx.x >> 3;     // batch pair 0..31
    const int g    = blockIdx.x & 7;      // neuron slice 0..7
    const int kseg = tid & 15;            // 32-k segment (fold dimension)
    const int jg   = tid >> 4;            // 0..31 -> 2 j rows each
    const int jb   = g * 64 + jg * 2;

    // ---- both weight micro-panels into registers (64 + 64 floats) ----
    float4 wh[2][8], wi[2][8];
    #pragma unroll
    for (int jx = 0; jx < 2; ++jx) {
        const float* hr = whh + (size_t)(jb + jx) * HSZ + kseg * 32;
        const float* ir = wih + (size_t)(jb + jx) * ISZ + kseg * 32;
        #pragma unroll
        for (int i = 0; i < 8; ++i) {
            wh[jx][i] = *(const float4*)(hr + 4 * i);
            wi[jx][i] = *(const float4*)(ir + 4 * i);
        }
    }

    // poll pointers: word k=tid of both batches of this pair
    unsigned long long* exw0 = ex + (size_t)(2 * p + 0) * 512 + tid;
    unsigned long long* exw1 = ex + (size_t)(2 * p + 1) * 512 + tid;

    // hl scatter offset for polled word k=tid (float index, b=0; b=1 adds 576)
    const int whf = ((tid >> 5) * 9 + ((tid >> 2) & 7)) * 4 + (tid & 3);

    // x staging role: thread covers (bx, io..io+1), coalesced float2
    const int bx = tid >> 8;
    const int io = (tid & 255) * 2;
    const int xf = ((bx * 16 + (io >> 5)) * 9 + ((io >> 2) & 7)) * 4 + (io & 3);
    const float* xsrc = x + (size_t)(2 * p + bx) * ISZ + io;

    // designated-lane roles (valid for kseg<4; harmless garbage otherwise)
    const int jxr  = kseg >> 1;
    const int br   = kseg & 1;
    const int outj = jb + (jxr & 1);
    const int outb = 2 * p + br;
    float* outp = out + (size_t)outb * HSZ + outj;                 // + t*B*H
    unsigned long long* exself = ex + (size_t)outb * 512 + outj;   // + slot*EXN

    // ---- prologue: stage x(0) (par 0), compute xw(0) ----
    {
        const float2 v = *(const float2*)xsrc;
        *(float2*)&xss[xf] = v;
    }
    __syncthreads();
    float xwv = dot_fold_pick(wi, xs4, 0, kseg, jxr, br);

    for (int t = 0; t < T_STEPS; ++t) {
        const int  parh  = (t & 1) * 288;          // f4 base for hls
        const bool havex = (t < T_STEPS - 1);

        // issue x(t+1) prefetch early: HBM latency hides under the poll
        float2 xv;
        if (havex) xv = *(const float2*)(xsrc + (size_t)(t + 1) * (BATCH * ISZ));

        if (t > 0) {
            const size_t soff = (size_t)((t - 1) & 1) * EXN;
            unsigned long long v0 = __hip_atomic_load(exw0 + soff, __ATOMIC_RELAXED,
                                                      __HIP_MEMORY_SCOPE_AGENT);
            unsigned long long v1 = __hip_atomic_load(exw1 + soff, __ATOMIC_RELAXED,
                                                      __HIP_MEMORY_SCOPE_AGENT);
            while ((unsigned)(v0 >> 32) != (unsigned)t ||
                   (unsigned)(v1 >> 32) != (unsigned)t) {
                __builtin_amdgcn_s_sleep(1);
                v0 = __hip_atomic_load(exw0 + soff, __ATOMIC_RELAXED,
                                       __HIP_MEMORY_SCOPE_AGENT);
                v1 = __hip_atomic_load(exw1 + soff, __ATOMIC_RELAXED,
                                       __HIP_MEMORY_SCOPE_AGENT);
            }
            union { unsigned u; float f; } c0, c1;
            c0.u = (unsigned)v0; c1.u = (unsigned)v1;
            hls[parh * 4 + whf]       = c0.f;     // batch 0
            hls[parh * 4 + 576 + whf] = c1.f;     // batch 1
        }
        if (havex) *(float2*)&xss[((t + 1) & 1) * 1152 + xf] = xv;
        __syncthreads();                           // single barrier per step

        float acc = 0.f;
        if (t > 0)
            acc = dot_fold_pick(wh, hl4, parh, kseg, jxr, br);

        if (kseg < 4) {                            // 4 designated lanes / group
            const float a2 = acc + xwv;
            const float e  = __expf(2.f * a2);     // tanh = (e-1)/(e+1)
            const float hv = 1.f - 2.f / (e + 1.f);
            outp[(size_t)t * (BATCH * HSZ)] = hv;
            if (havex)
                ex_store(exself + (size_t)(t & 1) * EXN, hv, (unsigned)(t + 1));
            else
                out[(size_t)T_STEPS * BATCH * HSZ + (size_t)outb * HSZ + outj] = hv;
        }

        // xw(t+1): independent of the exchange -> fills the propagation window
        if (havex)
            xwv = dot_fold_pick(wi, xs4, ((t + 1) & 1) * 288, kseg, jxr, br);
    }
}

// ---------------------------------------------------------------------------
extern "C" void kernel_launch(void* const* d_in, const int* in_sizes, int n_in,
                              void* d_out, int out_size, void* d_ws, size_t ws_size,
                              hipStream_t stream) {
    (void)in_sizes; (void)n_in; (void)out_size; (void)ws_size;
    const float* x   = (const float*)d_in[0];   // (512,64,512)
    const float* wih = (const float*)d_in[1];   // (512,512)
    const float* whh = (const float*)d_in[2];   // (512,512)
    float*       out = (float*)d_out;           // h_all (T,B,H) ++ h_last (B,H)
    unsigned long long* ex = (unsigned long long*)d_ws;   // 2*EXN u64 = 512 KB

    // zero the exchange tags (harness poisons d_ws each launch)
    (void)hipMemsetAsync(d_ws, 0, 2 * EXN * sizeof(unsigned long long), stream);

    hipLaunchKernelGGL(rnn_fused, dim3(256), dim3(512), 0, stream,
                       x, wih, whh, out, ex);
}

// Round 2
// 1125.494 us; speedup vs baseline: 1.0202x; 1.0033x over previous
//
#include <hip/hip_runtime.h>
#include <cmath>

#define T_STEPS 512
#define BATCH   64
#define ISZ     512
#define HSZ     512
#define EXN     32768   // u64 words per ring slot (64 batches x 512)

// ---------------------------------------------------------------------------
// Tagged-word exchange (proven protocol): one atomic u64 = {tag=t+1, h bits}.
// ---------------------------------------------------------------------------
__device__ __forceinline__ void ex_store(unsigned long long* w, float h, unsigned tag) {
    union { float f; unsigned u; } c; c.f = h;
    const unsigned long long v = ((unsigned long long)tag << 32) | (unsigned long long)c.u;
    __hip_atomic_store(w, v, __ATOMIC_RELAXED, __HIP_MEMORY_SCOPE_AGENT);
}

// Opaque register barrier: forces v into VGPRs and forbids the compiler from
// re-materializing it as a (loop-invariant) global load inside the t-loop.
#define KEEP4(v) asm volatile("" : "+v"((v).x), "+v"((v).y), "+v"((v).z), "+v"((v).w))

// ---------------------------------------------------------------------------
// Per-thread dot over a 32-k segment for 2 output rows x 2 batches, then
// in-wave butterfly fold over the 16 ksegs (lane bits 0..3), then pick this
// lane's (jx,b) result. src layout: float4[par*288 + (b*16 + kseg)*9 + i]
// (9-f4 row pad -> kseg bank stride 4, 2-way aliasing = free).
// ---------------------------------------------------------------------------
__device__ __forceinline__ float dot_fold_pick(const float4 (&W)[2][8],
                                               const float4* __restrict__ src,
                                               int parbase4, int kseg,
                                               int jxr, int br) {
    float A00 = 0.f, A01 = 0.f, A10 = 0.f, A11 = 0.f;
    const float4* s0 = src + parbase4 + kseg * 9;   // batch 0
    const float4* s1 = s0 + 144;                    // batch 1 (+16*9 f4)
    #pragma unroll
    for (int i = 0; i < 8; ++i) {
        const float4 h0 = s0[i];
        const float4 h1 = s1[i];
        A00 = fmaf(W[0][i].x, h0.x, A00); A00 = fmaf(W[0][i].y, h0.y, A00);
        A00 = fmaf(W[0][i].z, h0.z, A00); A00 = fmaf(W[0][i].w, h0.w, A00);
        A01 = fmaf(W[0][i].x, h1.x, A01); A01 = fmaf(W[0][i].y, h1.y, A01);
        A01 = fmaf(W[0][i].z, h1.z, A01); A01 = fmaf(W[0][i].w, h1.w, A01);
        A10 = fmaf(W[1][i].x, h0.x, A10); A10 = fmaf(W[1][i].y, h0.y, A10);
        A10 = fmaf(W[1][i].z, h0.z, A10); A10 = fmaf(W[1][i].w, h0.w, A10);
        A11 = fmaf(W[1][i].x, h1.x, A11); A11 = fmaf(W[1][i].y, h1.y, A11);
        A11 = fmaf(W[1][i].w, h1.w, A11); A11 = fmaf(W[1][i].z, h1.z, A11);
    }
    #pragma unroll
    for (int d = 1; d < 16; d <<= 1) {
        A00 += __shfl_xor(A00, d, 64);
        A01 += __shfl_xor(A01, d, 64);
        A10 += __shfl_xor(A10, d, 64);
        A11 += __shfl_xor(A11, d, 64);
    }
    const float a0 = br ? A01 : A00;
    const float a1 = br ? A11 : A10;
    return jxr ? a1 : a0;
}

// ---------------------------------------------------------------------------
// Fully fused RNN: 256 WGs x 512 threads, 1 WG/CU.
// Cluster swizzle: the 8 WGs sharing a batch pair (the ONLY communicators)
// land on one XCD (bid%8 = XCD round-robin heuristic): exchange words and x
// rows stay in one L2. Weights (W_hh + W_ih micro-panels, 128 f32/thread)
// are PINNED in VGPRs via KEEP4 -- previous build streamed them from L2
// every step (VGPR_Count=92 < 128), making the kernel L2-BW-bound.
// ---------------------------------------------------------------------------
__global__ __launch_bounds__(512, 2) void rnn_fused(const float* __restrict__ x,
                                                    const float* __restrict__ wih,
                                                    const float* __restrict__ whh,
                                                    float* __restrict__ out,
                                                    unsigned long long* __restrict__ ex) {
    __shared__ __align__(16) float hls[2304];   // [2 par][2 b][16 kseg][9 f4]
    __shared__ __align__(16) float xss[2304];   // same layout, x(t) rows
    const float4* hl4 = (const float4*)hls;
    const float4* xs4 = (const float4*)xss;

    const int tid  = threadIdx.x;
    const int bid  = blockIdx.x;
    const int xcd  = bid & 7;             // XCD under round-robin dispatch
    const int ib   = bid >> 3;            // 0..31 within XCD
    const int p    = xcd * 4 + (ib & 3);  // batch pair 0..31 (4 clusters/XCD)
    const int g    = ib >> 2;             // neuron slice 0..7
    const int kseg = tid & 15;            // 32-k segment (fold dimension)
    const int jg   = tid >> 4;            // 0..31 -> 2 j rows each
    const int jb   = g * 64 + jg * 2;

    // ---- both weight micro-panels into registers (64 + 64 floats) ----
    float4 wh[2][8], wi[2][8];
    #pragma unroll
    for (int jx = 0; jx < 2; ++jx) {
        const float* hr = whh + (size_t)(jb + jx) * HSZ + kseg * 32;
        const float* ir = wih + (size_t)(jb + jx) * ISZ + kseg * 32;
        #pragma unroll
        for (int i = 0; i < 8; ++i) {
            wh[jx][i] = *(const float4*)(hr + 4 * i);
            wi[jx][i] = *(const float4*)(ir + 4 * i);
        }
    }
    #pragma unroll
    for (int jx = 0; jx < 2; ++jx)
        #pragma unroll
        for (int i = 0; i < 8; ++i) { KEEP4(wh[jx][i]); KEEP4(wi[jx][i]); }

    // poll pointers: word k=tid of both batches of this pair
    unsigned long long* exw0 = ex + (size_t)(2 * p + 0) * 512 + tid;
    unsigned long long* exw1 = ex + (size_t)(2 * p + 1) * 512 + tid;

    // hl scatter offset for polled word k=tid (float index, b=0; b=1 adds 576)
    const int whf = ((tid >> 5) * 9 + ((tid >> 2) & 7)) * 4 + (tid & 3);

    // x staging role: thread covers (bx, io..io+1), coalesced float2
    const int bx = tid >> 8;
    const int io = (tid & 255) * 2;
    const int xf = ((bx * 16 + (io >> 5)) * 9 + ((io >> 2) & 7)) * 4 + (io & 3);
    const float* xsrc = x + (size_t)(2 * p + bx) * ISZ + io;

    // designated-lane roles (valid for kseg<4; harmless garbage otherwise)
    const int jxr  = kseg >> 1;
    const int br   = kseg & 1;
    const int outj = jb + (jxr & 1);
    const int outb = 2 * p + br;
    float* outp = out + (size_t)outb * HSZ + outj;                 // + t*B*H
    unsigned long long* exself = ex + (size_t)outb * 512 + outj;   // + slot*EXN

    // ---- prologue: stage x(0) (par 0), compute xw(0) ----
    {
        const float2 v = *(const float2*)xsrc;
        *(float2*)&xss[xf] = v;
    }
    __syncthreads();
    float xwv = dot_fold_pick(wi, xs4, 0, kseg, jxr, br);

    for (int t = 0; t < T_STEPS; ++t) {
        const int  parh  = (t & 1) * 288;          // f4 base for hls
        const bool havex = (t < T_STEPS - 1);

        // issue x(t+1) prefetch early: HBM latency hides under the poll
        float2 xv;
        if (havex) xv = *(const float2*)(xsrc + (size_t)(t + 1) * (BATCH * ISZ));

        if (t > 0) {
            const size_t soff = (size_t)((t - 1) & 1) * EXN;
            unsigned long long v0 = __hip_atomic_load(exw0 + soff, __ATOMIC_RELAXED,
                                                      __HIP_MEMORY_SCOPE_AGENT);
            unsigned long long v1 = __hip_atomic_load(exw1 + soff, __ATOMIC_RELAXED,
                                                      __HIP_MEMORY_SCOPE_AGENT);
            while ((unsigned)(v0 >> 32) != (unsigned)t ||
                   (unsigned)(v1 >> 32) != (unsigned)t) {
                __builtin_amdgcn_s_sleep(1);
                v0 = __hip_atomic_load(exw0 + soff, __ATOMIC_RELAXED,
                                       __HIP_MEMORY_SCOPE_AGENT);
                v1 = __hip_atomic_load(exw1 + soff, __ATOMIC_RELAXED,
                                       __HIP_MEMORY_SCOPE_AGENT);
            }
            union { unsigned u; float f; } c0, c1;
            c0.u = (unsigned)v0; c1.u = (unsigned)v1;
            hls[parh * 4 + whf]       = c0.f;     // batch 0
            hls[parh * 4 + 576 + whf] = c1.f;     // batch 1
        }
        if (havex) *(float2*)&xss[((t + 1) & 1) * 1152 + xf] = xv;
        __syncthreads();                           // single barrier per step

        float acc = 0.f;
        if (t > 0)
            acc = dot_fold_pick(wh, hl4, parh, kseg, jxr, br);

        if (kseg < 4) {                            // 4 designated lanes / group
            const float a2 = acc + xwv;
            const float e  = __expf(2.f * a2);     // tanh = (e-1)/(e+1)
            const float hv = 1.f - 2.f / (e + 1.f);
            outp[(size_t)t * (BATCH * HSZ)] = hv;
            if (havex)
                ex_store(exself + (size_t)(t & 1) * EXN, hv, (unsigned)(t + 1));
            else
                out[(size_t)T_STEPS * BATCH * HSZ + (size_t)outb * HSZ + outj] = hv;
        }

        // xw(t+1): independent of the exchange -> fills the propagation window
        if (havex)
            xwv = dot_fold_pick(wi, xs4, ((t + 1) & 1) * 288, kseg, jxr, br);
    }
}

// ---------------------------------------------------------------------------
extern "C" void kernel_launch(void* const* d_in, const int* in_sizes, int n_in,
                              void* d_out, int out_size, void* d_ws, size_t ws_size,
                              hipStream_t stream) {
    (void)in_sizes; (void)n_in; (void)out_size; (void)ws_size;
    const float* x   = (const float*)d_in[0];   // (512,64,512)
    const float* wih = (const float*)d_in[1];   // (512,512)
    const float* whh = (const float*)d_in[2];   // (512,512)
    float*       out = (float*)d_out;           // h_all (T,B,H) ++ h_last (B,H)
    unsigned long long* ex = (unsigned long long*)d_ws;   // 2*EXN u64 = 512 KB

    // zero the exchange tags (harness poisons d_ws each launch)
    (void)hipMemsetAsync(d_ws, 0, 2 * EXN * sizeof(unsigned long long), stream);

    hipLaunchKernelGGL(rnn_fused, dim3(256), dim3(512), 0, stream,
                       x, wih, whh, out, ex);
}

// Round 3
// 1038.158 us; speedup vs baseline: 1.1061x; 1.0841x over previous
//
#include <hip/hip_runtime.h>
#include <cmath>

#define T_STEPS 512
#define BATCH   64
#define ISZ     512
#define HSZ     512
#define EXN     32768   // u64 words per ring slot (64 batches x 512)

// ---------------------------------------------------------------------------
// Tagged-word exchange (proven protocol): one atomic u64 = {tag=t+1, h bits}.
// ---------------------------------------------------------------------------
__device__ __forceinline__ void ex_store(unsigned long long* w, float h, unsigned tag) {
    union { float f; unsigned u; } c; c.f = h;
    const unsigned long long v = ((unsigned long long)tag << 32) | (unsigned long long)c.u;
    __hip_atomic_store(w, v, __ATOMIC_RELAXED, __HIP_MEMORY_SCOPE_AGENT);
}

// ---------------------------------------------------------------------------
// 16-k-segment dot for 4 output rows x 2 batches, then interleaved merging
// butterfly over the 32 ksegs (lane bits 0..4): 9 shfls total (vs 16-per-4acc
// naive). Lane kseg<8 ends with the full dot for
//   row = ((kseg>>1)&1) + 2*((kseg>>2)&1),  batch = kseg&1.
// LDS layout: float4[par*320 + b*160 + kseg*5 + i]  (stride 5 f4 -> minimal
// 4-way bank aliasing for 32 distinct b128 addrs; 2-way lane broadcast free).
// ---------------------------------------------------------------------------
__device__ __forceinline__ float dot16_fold(const float4 (&W)[4][4],
                                            const float4* __restrict__ src,
                                            int parbase4, int kseg) {
    const float4* s0 = src + parbase4 + kseg * 5;   // batch 0
    const float4* s1 = s0 + 160;                    // batch 1
    float A0 = 0.f, A1 = 0.f, A2 = 0.f, A3 = 0.f;   // rows 0..3, batch 0
    float B0 = 0.f, B1 = 0.f, B2 = 0.f, B3 = 0.f;   // rows 0..3, batch 1
    #pragma unroll
    for (int i = 0; i < 4; ++i) {
        const float4 h0 = s0[i];
        const float4 h1 = s1[i];
        const float4 w0 = W[0][i], w1 = W[1][i], w2 = W[2][i], w3 = W[3][i];
        A0 = fmaf(w0.x, h0.x, A0); A0 = fmaf(w0.y, h0.y, A0);
        A0 = fmaf(w0.z, h0.z, A0); A0 = fmaf(w0.w, h0.w, A0);
        A1 = fmaf(w1.x, h0.x, A1); A1 = fmaf(w1.y, h0.y, A1);
        A1 = fmaf(w1.z, h0.z, A1); A1 = fmaf(w1.w, h0.w, A1);
        A2 = fmaf(w2.x, h0.x, A2); A2 = fmaf(w2.y, h0.y, A2);
        A2 = fmaf(w2.z, h0.z, A2); A2 = fmaf(w2.w, h0.w, A2);
        A3 = fmaf(w3.x, h0.x, A3); A3 = fmaf(w3.y, h0.y, A3);
        A3 = fmaf(w3.z, h0.z, A3); A3 = fmaf(w3.w, h0.w, A3);
        B0 = fmaf(w0.x, h1.x, B0); B0 = fmaf(w0.y, h1.y, B0);
        B0 = fmaf(w0.z, h1.z, B0); B0 = fmaf(w0.w, h1.w, B0);
        B1 = fmaf(w1.x, h1.x, B1); B1 = fmaf(w1.y, h1.y, B1);
        B1 = fmaf(w1.z, h1.z, B1); B1 = fmaf(w1.w, h1.w, B1);
        B2 = fmaf(w2.x, h1.x, B2); B2 = fmaf(w2.y, h1.y, B2);
        B2 = fmaf(w2.z, h1.z, B2); B2 = fmaf(w2.w, h1.w, B2);
        B3 = fmaf(w3.x, h1.x, B3); B3 = fmaf(w3.y, h1.y, B3);
        B3 = fmaf(w3.z, h1.z, B3); B3 = fmaf(w3.w, h1.w, B3);
    }
    const bool sb0 = (kseg & 1) != 0;   // lane keeps batch sb0
    const bool sb1 = (kseg & 2) != 0;   // then row-pair select
    const bool sb2 = (kseg & 4) != 0;   // then row-quad select
    // level 1 (d=1): fold batch dim, accs 8 -> 4
    const float u0 = (sb0 ? B0 : A0) + __shfl_xor(sb0 ? A0 : B0, 1, 64);
    const float u1 = (sb0 ? B1 : A1) + __shfl_xor(sb0 ? A1 : B1, 1, 64);
    const float u2 = (sb0 ? B2 : A2) + __shfl_xor(sb0 ? A2 : B2, 1, 64);
    const float u3 = (sb0 ? B3 : A3) + __shfl_xor(sb0 ? A3 : B3, 1, 64);
    // level 2 (d=2): fold row pairs, 4 -> 2
    const float w01 = (sb1 ? u1 : u0) + __shfl_xor(sb1 ? u0 : u1, 2, 64);
    const float w23 = (sb1 ? u3 : u2) + __shfl_xor(sb1 ? u2 : u3, 2, 64);
    // level 3 (d=4): fold row quads, 2 -> 1
    float z = (sb2 ? w23 : w01) + __shfl_xor(sb2 ? w01 : w23, 4, 64);
    // levels 4,5: plain lane fold
    z += __shfl_xor(z, 8, 64);
    z += __shfl_xor(z, 16, 64);
    return z;
}

// ---------------------------------------------------------------------------
// Fully fused RNN: 256 WGs x 512 threads, 1 WG/CU, cluster-per-XCD swizzle
// (proven round 2: FETCH 788->106 MB). Thread (jg 0..15, kseg 0..31) owns
// 4 j-rows x 16 k x 2 batches. Weights = 64+64 f32/thread, made
// non-rematerializable via an asm-opaque zero added into every component
// (plain KEEP4 was defeated: VGPR stayed 92 -> weights streamed from L2
// every step, ~1.9 us/step L2 floor). DS pipe work halved vs round 2:
// 16 b128 reads + 18 shfls per wave-step (was 32 + 32).
// ---------------------------------------------------------------------------
__global__ __launch_bounds__(512, 2) void rnn_fused(const float* __restrict__ x,
                                                    const float* __restrict__ wih,
                                                    const float* __restrict__ whh,
                                                    float* __restrict__ out,
                                                    unsigned long long* __restrict__ ex) {
    __shared__ __align__(16) float hls[2560];   // [2 par][2 b][32 kseg][5 f4]
    __shared__ __align__(16) float xss[2560];   // same layout, x rows
    const float4* hl4 = (const float4*)hls;
    const float4* xs4 = (const float4*)xss;

    const int tid  = threadIdx.x;
    const int bid  = blockIdx.x;
    const int xcd  = bid & 7;             // XCD under round-robin dispatch
    const int ib   = bid >> 3;            // 0..31 within XCD
    const int p    = xcd * 4 + (ib & 3);  // batch pair (4 clusters/XCD)
    const int g    = ib >> 2;             // neuron slice 0..7
    const int kseg = tid & 31;            // 16-wide k segment
    const int jg   = tid >> 5;            // 0..15 -> 4 j rows each
    const int jb   = g * 64 + jg * 4;

    // ---- weight micro-panels: 4 rows x 16 k of W_hh and W_ih ----
    float4 wh[4][4], wi[4][4];
    #pragma unroll
    for (int r = 0; r < 4; ++r) {
        const float* hr = whh + (size_t)(jb + r) * HSZ + kseg * 16;
        const float* ir = wih + (size_t)(jb + r) * ISZ + kseg * 16;
        #pragma unroll
        for (int i = 0; i < 4; ++i) {
            wh[r][i] = *(const float4*)(hr + 4 * i);
            wi[r][i] = *(const float4*)(ir + 4 * i);
        }
    }
    // Opaque zero: weights become load+add(reg) -> not single-instruction
    // rematerializable -> must stay VGPR-resident (or spill visibly).
    float oz;
    asm volatile("v_mov_b32 %0, 0" : "=v"(oz));
    #pragma unroll
    for (int r = 0; r < 4; ++r)
        #pragma unroll
        for (int i = 0; i < 4; ++i) {
            wh[r][i].x += oz; wh[r][i].y += oz; wh[r][i].z += oz; wh[r][i].w += oz;
            wi[r][i].x += oz; wi[r][i].y += oz; wi[r][i].z += oz; wi[r][i].w += oz;
        }

    // poll pointers: word k=tid of both batches of this pair
    unsigned long long* exw0 = ex + (size_t)(2 * p + 0) * 512 + tid;
    unsigned long long* exw1 = ex + (size_t)(2 * p + 1) * 512 + tid;

    // hl scatter offset for polled word k=tid (float idx; b=1 adds 640)
    const int whf = (tid >> 4) * 20 + ((tid >> 2) & 3) * 4 + (tid & 3);

    // x staging role: thread covers (bx, io..io+1), coalesced float2
    const int bx = tid >> 8;
    const int io = (tid & 255) * 2;
    const int xf = bx * 640 + (io >> 4) * 20 + ((io >> 2) & 3) * 4 + (io & 3);
    const float* xsrc = x + (size_t)(2 * p + bx) * ISZ + io;

    // designated-lane roles (valid for kseg<8)
    const int row  = ((kseg >> 1) & 1) + 2 * ((kseg >> 2) & 1);
    const int br   = kseg & 1;
    const int outj = jb + row;
    const int outb = 2 * p + br;
    float* outp = out + (size_t)outb * HSZ + outj;                 // + t*B*H
    unsigned long long* exself = ex + (size_t)outb * 512 + outj;   // + slot*EXN

    // ---- prologue: stage x(0) (par 0), compute xw(0) ----
    {
        const float2 v = *(const float2*)xsrc;
        *(float2*)&xss[xf] = v;
    }
    __syncthreads();
    float xwv = dot16_fold(wi, xs4, 0, kseg);

    for (int t = 0; t < T_STEPS; ++t) {
        const int  parh4 = (t & 1) * 320;          // f4 base for hls
        const bool havex = (t < T_STEPS - 1);

        // issue x(t+1) prefetch early: HBM latency hides under the poll
        float2 xv;
        if (havex) xv = *(const float2*)(xsrc + (size_t)(t + 1) * (BATCH * ISZ));

        if (t > 0) {
            const size_t soff = (size_t)((t - 1) & 1) * EXN;
            unsigned long long v0 = __hip_atomic_load(exw0 + soff, __ATOMIC_RELAXED,
                                                      __HIP_MEMORY_SCOPE_AGENT);
            unsigned long long v1 = __hip_atomic_load(exw1 + soff, __ATOMIC_RELAXED,
                                                      __HIP_MEMORY_SCOPE_AGENT);
            while ((unsigned)(v0 >> 32) != (unsigned)t ||
                   (unsigned)(v1 >> 32) != (unsigned)t) {
                __builtin_amdgcn_s_sleep(1);
                v0 = __hip_atomic_load(exw0 + soff, __ATOMIC_RELAXED,
                                       __HIP_MEMORY_SCOPE_AGENT);
                v1 = __hip_atomic_load(exw1 + soff, __ATOMIC_RELAXED,
                                       __HIP_MEMORY_SCOPE_AGENT);
            }
            union { unsigned u; float f; } c0, c1;
            c0.u = (unsigned)v0; c1.u = (unsigned)v1;
            hls[parh4 * 4 + whf]       = c0.f;     // batch 0
            hls[parh4 * 4 + 640 + whf] = c1.f;     // batch 1
        }
        if (havex) *(float2*)&xss[((t + 1) & 1) * 1280 + xf] = xv;
        __syncthreads();                           // single barrier per step

        float acc = 0.f;
        if (t > 0)
            acc = dot16_fold(wh, hl4, parh4, kseg);

        if (kseg < 8) {                            // 8 designated lanes / 32
            const float a2 = acc + xwv;
            const float e  = __expf(2.f * a2);     // tanh = (e-1)/(e+1)
            const float hv = 1.f - 2.f / (e + 1.f);
            outp[(size_t)t * (BATCH * HSZ)] = hv;
            if (havex)
                ex_store(exself + (size_t)(t & 1) * EXN, hv, (unsigned)(t + 1));
            else
                out[(size_t)T_STEPS * BATCH * HSZ + (size_t)outb * HSZ + outj] = hv;
        }

        // xw(t+1): independent of the exchange -> fills the propagation window
        if (havex)
            xwv = dot16_fold(wi, xs4, ((t + 1) & 1) * 320, kseg);
    }
}

// ---------------------------------------------------------------------------
extern "C" void kernel_launch(void* const* d_in, const int* in_sizes, int n_in,
                              void* d_out, int out_size, void* d_ws, size_t ws_size,
                              hipStream_t stream) {
    (void)in_sizes; (void)n_in; (void)out_size; (void)ws_size;
    const float* x   = (const float*)d_in[0];   // (512,64,512)
    const float* wih = (const float*)d_in[1];   // (512,512)
    const float* whh = (const float*)d_in[2];   // (512,512)
    float*       out = (float*)d_out;           // h_all (T,B,H) ++ h_last (B,H)
    unsigned long long* ex = (unsigned long long*)d_ws;   // 2*EXN u64 = 512 KB

    // zero the exchange tags (harness poisons d_ws each launch)
    (void)hipMemsetAsync(d_ws, 0, 2 * EXN * sizeof(unsigned long long), stream);

    hipLaunchKernelGGL(rnn_fused, dim3(256), dim3(512), 0, stream,
                       x, wih, whh, out, ex);
}

// Round 4
// 1020.335 us; speedup vs baseline: 1.1254x; 1.0175x over previous
//
#include <hip/hip_runtime.h>
#include <cmath>

#define T_STEPS 512
#define BATCH   64
#define ISZ     512
#define HSZ     512
#define EXN     32768   // u64 words per ring slot (64 batches x 512)

// ---------------------------------------------------------------------------
// Tagged-word exchange (proven protocol): one atomic u64 = {tag=t+1, h bits}.
// ---------------------------------------------------------------------------
__device__ __forceinline__ void ex_store(unsigned long long* w, float h, unsigned tag) {
    union { float f; unsigned u; } c; c.f = h;
    const unsigned long long v = ((unsigned long long)tag << 32) | (unsigned long long)c.u;
    __hip_atomic_store(w, v, __ATOMIC_RELAXED, __HIP_MEMORY_SCOPE_AGENT);
}

// ---------------------------------------------------------------------------
// Volatile-asm 16B load: the compiler may NOT duplicate, sink, or remat a
// volatile asm, so values loaded this way MUST stay register-resident across
// the t-loop (or spill visibly). Rounds 1-3 proved that compiler-generated
// loads get re-executed from L2 every step (VGPR stuck at 92), leaving the
// kernel L2-BW-bound at ~1.9 us/step on weight re-fetch.
// ---------------------------------------------------------------------------
__device__ __forceinline__ float4 ld_pin_f4(const float* p) {
    float4 v;
    asm volatile("global_load_dwordx4 %0, %1, off" : "=v"(v) : "v"(p));
    return v;
}

// ---------------------------------------------------------------------------
// 16-k-segment dot for 4 output rows x 2 batches, then interleaved merging
// butterfly over the 32 ksegs (lane bits 0..4): 9+2 shfls total. Lane kseg<8
// ends with the full dot for row = ((kseg>>1)&1)+2*((kseg>>2)&1), b = kseg&1.
// LDS layout: float4[par*320 + b*160 + kseg*5 + i]  (stride 5 f4).
// ---------------------------------------------------------------------------
__device__ __forceinline__ float dot16_fold(const float4 (&W)[4][4],
                                            const float4* __restrict__ src,
                                            int parbase4, int kseg) {
    const float4* s0 = src + parbase4 + kseg * 5;   // batch 0
    const float4* s1 = s0 + 160;                    // batch 1
    float A0 = 0.f, A1 = 0.f, A2 = 0.f, A3 = 0.f;   // rows 0..3, batch 0
    float B0 = 0.f, B1 = 0.f, B2 = 0.f, B3 = 0.f;   // rows 0..3, batch 1
    #pragma unroll
    for (int i = 0; i < 4; ++i) {
        const float4 h0 = s0[i];
        const float4 h1 = s1[i];
        const float4 w0 = W[0][i], w1 = W[1][i], w2 = W[2][i], w3 = W[3][i];
        A0 = fmaf(w0.x, h0.x, A0); A0 = fmaf(w0.y, h0.y, A0);
        A0 = fmaf(w0.z, h0.z, A0); A0 = fmaf(w0.w, h0.w, A0);
        A1 = fmaf(w1.x, h0.x, A1); A1 = fmaf(w1.y, h0.y, A1);
        A1 = fmaf(w1.z, h0.z, A1); A1 = fmaf(w1.w, h0.w, A1);
        A2 = fmaf(w2.x, h0.x, A2); A2 = fmaf(w2.y, h0.y, A2);
        A2 = fmaf(w2.z, h0.z, A2); A2 = fmaf(w2.w, h0.w, A2);
        A3 = fmaf(w3.x, h0.x, A3); A3 = fmaf(w3.y, h0.y, A3);
        A3 = fmaf(w3.z, h0.z, A3); A3 = fmaf(w3.w, h0.w, A3);
        B0 = fmaf(w0.x, h1.x, B0); B0 = fmaf(w0.y, h1.y, B0);
        B0 = fmaf(w0.z, h1.z, B0); B0 = fmaf(w0.w, h1.w, B0);
        B1 = fmaf(w1.x, h1.x, B1); B1 = fmaf(w1.y, h1.y, B1);
        B1 = fmaf(w1.z, h1.z, B1); B1 = fmaf(w1.w, h1.w, B1);
        B2 = fmaf(w2.x, h1.x, B2); B2 = fmaf(w2.y, h1.y, B2);
        B2 = fmaf(w2.z, h1.z, B2); B2 = fmaf(w2.w, h1.w, B2);
        B3 = fmaf(w3.x, h1.x, B3); B3 = fmaf(w3.y, h1.y, B3);
        B3 = fmaf(w3.z, h1.z, B3); B3 = fmaf(w3.w, h1.w, B3);
    }
    const bool sb0 = (kseg & 1) != 0;   // lane keeps batch sb0
    const bool sb1 = (kseg & 2) != 0;   // then row-pair select
    const bool sb2 = (kseg & 4) != 0;   // then row-quad select
    // level 1 (d=1): fold batch dim, accs 8 -> 4
    const float u0 = (sb0 ? B0 : A0) + __shfl_xor(sb0 ? A0 : B0, 1, 64);
    const float u1 = (sb0 ? B1 : A1) + __shfl_xor(sb0 ? A1 : B1, 1, 64);
    const float u2 = (sb0 ? B2 : A2) + __shfl_xor(sb0 ? A2 : B2, 1, 64);
    const float u3 = (sb0 ? B3 : A3) + __shfl_xor(sb0 ? A3 : B3, 1, 64);
    // level 2 (d=2): fold row pairs, 4 -> 2
    const float w01 = (sb1 ? u1 : u0) + __shfl_xor(sb1 ? u0 : u1, 2, 64);
    const float w23 = (sb1 ? u3 : u2) + __shfl_xor(sb1 ? u2 : u3, 2, 64);
    // level 3 (d=4): fold row quads, 2 -> 1
    float z = (sb2 ? w23 : w01) + __shfl_xor(sb2 ? w01 : w23, 4, 64);
    // levels 4,5: plain lane fold
    z += __shfl_xor(z, 8, 64);
    z += __shfl_xor(z, 16, 64);
    return z;
}

// ---------------------------------------------------------------------------
// Fully fused RNN: 256 WGs x 512 threads, 1 WG/CU, cluster-per-XCD swizzle
// (proven: FETCH 788->106 MB). Thread (jg 0..15, kseg 0..31) owns 4 j-rows x
// 16 k x 2 batches. W_hh + W_ih micro-panels (128 f32/thread) pinned in
// VGPRs via volatile-asm loads (un-defeatable, unlike KEEP4/opaque-zero).
// ---------------------------------------------------------------------------
__global__ __launch_bounds__(512, 2) void rnn_fused(const float* __restrict__ x,
                                                    const float* __restrict__ wih,
                                                    const float* __restrict__ whh,
                                                    float* __restrict__ out,
                                                    unsigned long long* __restrict__ ex) {
    __shared__ __align__(16) float hls[2560];   // [2 par][2 b][32 kseg][5 f4]
    __shared__ __align__(16) float xss[2560];   // same layout, x rows
    const float4* hl4 = (const float4*)hls;
    const float4* xs4 = (const float4*)xss;

    const int tid  = threadIdx.x;
    const int bid  = blockIdx.x;
    const int xcd  = bid & 7;             // XCD under round-robin dispatch
    const int ib   = bid >> 3;            // 0..31 within XCD
    const int p    = xcd * 4 + (ib & 3);  // batch pair (4 clusters/XCD)
    const int g    = ib >> 2;             // neuron slice 0..7
    const int kseg = tid & 31;            // 16-wide k segment
    const int jg   = tid >> 5;            // 0..15 -> 4 j rows each
    const int jb   = g * 64 + jg * 4;

    // ---- weight micro-panels: 4 rows x 16 k, via pinned volatile-asm loads ----
    float4 wh[4][4], wi[4][4];
    #pragma unroll
    for (int r = 0; r < 4; ++r) {
        const float* hr = whh + (size_t)(jb + r) * HSZ + kseg * 16;
        const float* ir = wih + (size_t)(jb + r) * ISZ + kseg * 16;
        #pragma unroll
        for (int i = 0; i < 4; ++i) {
            wh[r][i] = ld_pin_f4(hr + 4 * i);
            wi[r][i] = ld_pin_f4(ir + 4 * i);
        }
    }
    asm volatile("s_waitcnt vmcnt(0)" ::: "memory");
    __builtin_amdgcn_sched_barrier(0);    // rule #18: no consumer hoisting

    // poll pointers: word k=tid of both batches of this pair
    unsigned long long* exw0 = ex + (size_t)(2 * p + 0) * 512 + tid;
    unsigned long long* exw1 = ex + (size_t)(2 * p + 1) * 512 + tid;

    // hl scatter offset for polled word k=tid (float idx; b=1 adds 640)
    const int whf = (tid >> 4) * 20 + ((tid >> 2) & 3) * 4 + (tid & 3);

    // x staging role: thread covers (bx, io..io+1), coalesced float2
    const int bx = tid >> 8;
    const int io = (tid & 255) * 2;
    const int xf = bx * 640 + (io >> 4) * 20 + ((io >> 2) & 3) * 4 + (io & 3);
    const float* xsrc = x + (size_t)(2 * p + bx) * ISZ + io;

    // designated-lane roles (valid for kseg<8)
    const int row  = ((kseg >> 1) & 1) + 2 * ((kseg >> 2) & 1);
    const int br   = kseg & 1;
    const int outj = jb + row;
    const int outb = 2 * p + br;
    float* outp = out + (size_t)outb * HSZ + outj;                 // + t*B*H
    unsigned long long* exself = ex + (size_t)outb * 512 + outj;   // + slot*EXN

    // ---- prologue: stage x(0) (par 0), compute xw(0) ----
    {
        const float2 v = *(const float2*)xsrc;
        *(float2*)&xss[xf] = v;
    }
    __syncthreads();
    float xwv = dot16_fold(wi, xs4, 0, kseg);

    for (int t = 0; t < T_STEPS; ++t) {
        const int  parh4 = (t & 1) * 320;          // f4 base for hls
        const bool havex = (t < T_STEPS - 1);

        // issue x(t+1) prefetch early: HBM latency hides under the poll
        float2 xv;
        if (havex) xv = *(const float2*)(xsrc + (size_t)(t + 1) * (BATCH * ISZ));

        if (t > 0) {
            const size_t soff = (size_t)((t - 1) & 1) * EXN;
            unsigned long long v0 = __hip_atomic_load(exw0 + soff, __ATOMIC_RELAXED,
                                                      __HIP_MEMORY_SCOPE_AGENT);
            unsigned long long v1 = __hip_atomic_load(exw1 + soff, __ATOMIC_RELAXED,
                                                      __HIP_MEMORY_SCOPE_AGENT);
            while ((unsigned)(v0 >> 32) != (unsigned)t ||
                   (unsigned)(v1 >> 32) != (unsigned)t) {
                __builtin_amdgcn_s_sleep(1);
                v0 = __hip_atomic_load(exw0 + soff, __ATOMIC_RELAXED,
                                       __HIP_MEMORY_SCOPE_AGENT);
                v1 = __hip_atomic_load(exw1 + soff, __ATOMIC_RELAXED,
                                       __HIP_MEMORY_SCOPE_AGENT);
            }
            union { unsigned u; float f; } c0, c1;
            c0.u = (unsigned)v0; c1.u = (unsigned)v1;
            hls[parh4 * 4 + whf]       = c0.f;     // batch 0
            hls[parh4 * 4 + 640 + whf] = c1.f;     // batch 1
        }
        if (havex) *(float2*)&xss[((t + 1) & 1) * 1280 + xf] = xv;
        __syncthreads();                           // single barrier per step

        float acc = 0.f;
        if (t > 0)
            acc = dot16_fold(wh, hl4, parh4, kseg);

        if (kseg < 8) {                            // 8 designated lanes / 32
            const float a2 = acc + xwv;
            const float e  = __expf(2.f * a2);     // tanh = (e-1)/(e+1)
            const float hv = 1.f - 2.f / (e + 1.f);
            outp[(size_t)t * (BATCH * HSZ)] = hv;
            if (havex)
                ex_store(exself + (size_t)(t & 1) * EXN, hv, (unsigned)(t + 1));
            else
                out[(size_t)T_STEPS * BATCH * HSZ + (size_t)outb * HSZ + outj] = hv;
        }

        // xw(t+1): independent of the exchange -> fills the propagation window
        if (havex)
            xwv = dot16_fold(wi, xs4, ((t + 1) & 1) * 320, kseg);
    }
}

// ---------------------------------------------------------------------------
extern "C" void kernel_launch(void* const* d_in, const int* in_sizes, int n_in,
                              void* d_out, int out_size, void* d_ws, size_t ws_size,
                              hipStream_t stream) {
    (void)in_sizes; (void)n_in; (void)out_size; (void)ws_size;
    const float* x   = (const float*)d_in[0];   // (512,64,512)
    const float* wih = (const float*)d_in[1];   // (512,512)
    const float* whh = (const float*)d_in[2];   // (512,512)
    float*       out = (float*)d_out;           // h_all (T,B,H) ++ h_last (B,H)
    unsigned long long* ex = (unsigned long long*)d_ws;   // 2*EXN u64 = 512 KB

    // zero the exchange tags (harness poisons d_ws each launch)
    (void)hipMemsetAsync(d_ws, 0, 2 * EXN * sizeof(unsigned long long), stream);

    hipLaunchKernelGGL(rnn_fused, dim3(256), dim3(512), 0, stream,
                       x, wih, whh, out, ex);
}